// Round 4
// baseline (752.854 us; speedup 1.0000x reference)
//
#include <hip/hip_runtime.h>
#include <hip/hip_bf16.h>
#include <stdint.h>

#define HID 128
#define BSHIFT 7
#define NBLK 64      // edge-slice blocks for count/place

typedef __attribute__((ext_vector_type(8))) __bf16 bf16x8;
typedef __attribute__((ext_vector_type(4))) float f32x4;

static __device__ __forceinline__ float bf2f(ushort h){
  union { uint u; float f; } c; c.u = ((uint)h) << 16; return c.f;
}
static __device__ __forceinline__ ushort f2bf(float f){
  union { float f; uint u; } c; c.f = f;
  uint u = c.u;
  return (ushort)((u + 0x7fffu + ((u >> 16) & 1u)) >> 16);
}
static __device__ __forceinline__ bf16x8 load8(const ushort* p){
  return *(const bf16x8*)p;
}

// ---------------- f32 -> bf16 convert (emb) ----------------
__global__ void k_cvt(const float* __restrict__ in, ushort* __restrict__ out, int n){
  int i = blockIdx.x * 256 + threadIdx.x;
  if (i < n) out[i] = f2bf(in[i]);
}

// ---- layer weights f32 -> bf16 frag-major: [layer][kt4][mat2][jt8][lane64][e8] ----
// Column permutation: C-tile jt, lane l16 -> global out col = l16*8 + jt, so each
// thread's 8 jt-accumulators hold 8 CONTIGUOUS output columns (dense 16B stores).
__global__ void k_cvtw(const float* __restrict__ Wl, const float* __restrict__ Wr,
                       ushort* __restrict__ outF, int total){
  int o = blockIdx.x * 256 + threadIdx.x;
  if (o >= total) return;
  int layer = o >> 15;
  int r = o & 32767;
  int e    = r & 7;
  int lane = (r >> 3) & 63;
  int jt   = (r >> 9) & 7;
  int mat  = (r >> 12) & 1;
  int kt   = r >> 13;
  int l16 = lane & 15, quad = lane >> 4;
  int j = l16 * 8 + jt;               // permuted output column
  int k = kt * 32 + quad * 8 + e;
  const float* W = mat ? Wr : Wl;
  outF[o] = f2bf(W[layer * 16384 + j * 128 + k]);
}

// ---- jk weights f32 -> bf16 frag-major: [kt16][jt8][lane64][e8] ----
// f32 output: col = l16*4 + (jt&3) + (jt>>2)*64 -> each thread holds 2 groups of
// 4 contiguous f32 cols (two dense dwordx4 stores per row).
__global__ void k_cvtjk(const float* __restrict__ jkW, ushort* __restrict__ outF){
  int o = blockIdx.x * 256 + threadIdx.x;   // total 65536
  int e    = o & 7;
  int lane = (o >> 3) & 63;
  int jt   = (o >> 9) & 7;
  int kt   = o >> 12;
  int l16 = lane & 15, quad = lane >> 4;
  int j = l16 * 4 + (jt & 3) + (jt >> 2) * 64;   // permuted output column
  int k = kt * 32 + quad * 8 + e;
  outF[o] = f2bf(jkW[j * 512 + k]);
}

// ================ deterministic two-level CSR build (no global atomics) ================
__global__ __launch_bounds__(1024) void k_count(
    const int* __restrict__ dst, int* __restrict__ rowcnt, int E, int NB, int es){
  __shared__ int h[1024];
  int blk = blockIdx.x;
  for (int i = threadIdx.x; i < NB; i += 1024) h[i] = 0;
  __syncthreads();
  int e0 = blk * es, e1 = min(e0 + es, E);
  for (int e = e0 + threadIdx.x; e < e1; e += 1024)
    atomicAdd(&h[dst[e] >> BSHIFT], 1);
  __syncthreads();
  for (int i = threadIdx.x; i < NB; i += 1024)
    rowcnt[blk * NB + i] = h[i];
}

__global__ __launch_bounds__(1024) void k_colscan(
    int* __restrict__ rowcnt, int* __restrict__ bbase, int NB, int nblk){
  int b = threadIdx.x;
  int total = 0;
  if (b < NB)
    for (int r = 0; r < nblk; r++) total += rowcnt[r * NB + b];
  int lane = b & 63, w = b >> 6;
  int x = total;
  #pragma unroll
  for (int d = 1; d < 64; d <<= 1){ int y = __shfl_up(x, d, 64); if (lane >= d) x += y; }
  __shared__ int tmp[16];
  if (lane == 63) tmp[w] = x;
  __syncthreads();
  if (b < 64){
    int s = (lane < 16) ? tmp[lane] : 0;
    #pragma unroll
    for (int d = 1; d < 16; d <<= 1){ int y = __shfl_up(s, d, 64); if (lane >= d) s += y; }
    if (lane < 16) tmp[lane] = s;
  }
  __syncthreads();
  int base = ((w > 0) ? tmp[w - 1] : 0) + x - total;  // exclusive
  if (b < NB){
    bbase[b] = base;
    int acc = base;
    for (int r = 0; r < nblk; r++){
      int v = rowcnt[r * NB + b];
      rowcnt[r * NB + b] = acc;
      acc += v;
    }
    if (b == NB - 1) bbase[NB] = acc;
  }
}

__global__ __launch_bounds__(1024) void k_place(
    const int* __restrict__ src, const int* __restrict__ dst,
    const int* __restrict__ rowcnt, uint* __restrict__ binned, int E, int NB, int es){
  __shared__ int cur[1024];
  int blk = blockIdx.x;
  for (int i = threadIdx.x; i < NB; i += 1024) cur[i] = rowcnt[blk * NB + i];
  __syncthreads();
  int e0 = blk * es, e1 = min(e0 + es, E);
  for (int e = e0 + threadIdx.x; e < e1; e += 1024){
    int d = dst[e];
    int b = d >> BSHIFT;
    int pos = atomicAdd(&cur[b], 1);
    binned[pos] = ((uint)src[e] << BSHIFT) | (uint)(d & 127);
  }
}

__global__ __launch_bounds__(256) void k_bpass(
    const uint* __restrict__ binned, const int* __restrict__ bbase,
    int* __restrict__ csr, int* __restrict__ offs, int* __restrict__ cnt, int N){
  int b = blockIdx.x;
  int n0 = b << BSHIFT;
  int tid = threadIdx.x;
  __shared__ int lcnt[128], loffs[128];
  if (tid < 128) lcnt[tid] = 0;
  __syncthreads();
  int base = bbase[b];
  int m = bbase[b + 1] - base;
  const uint* bp = binned + base;
  uint vv[12]; int slot[12];
  #pragma unroll
  for (int u = 0; u < 12; u++){
    int i = tid + u * 256;
    if (i < m){
      uint v = bp[i];
      vv[u] = v;
      slot[u] = atomicAdd(&lcnt[v & 127], 1);
    }
  }
  __syncthreads();
  if (tid < 64){
    int a0 = lcnt[tid * 2], a1 = lcnt[tid * 2 + 1];
    int s = a0 + a1;
    int x = s;
    #pragma unroll
    for (int d = 1; d < 64; d <<= 1){ int y = __shfl_up(x, d, 64); if (tid >= d) x += y; }
    int excl = x - s;
    loffs[tid * 2] = excl;
    loffs[tid * 2 + 1] = excl + a0;
  }
  __syncthreads();
  if (tid < 128 && n0 + tid < N){
    cnt[n0 + tid] = lcnt[tid];
    offs[n0 + tid] = base + loffs[tid];
  }
  #pragma unroll
  for (int u = 0; u < 12; u++){
    int i = tid + u * 256;
    if (i < m){
      uint v = vv[u];
      csr[base + loffs[v & 127] + slot[u]] = (int)(v >> BSHIFT);
    }
  }
}

// ---------------- scatter-mean aggregation v3 ----------------
__global__ __launch_bounds__(256) void k_aggregate(
    const ushort* __restrict__ x, const int* __restrict__ csr,
    const int* __restrict__ offs, const int* __restrict__ cnt,
    ushort* __restrict__ agg, int N){
  int node = blockIdx.x * 4 + (threadIdx.x >> 6);
  int lane = threadIdx.x & 63;
  if (node >= N) return;
  int half = lane >> 5;      // which edge of the pair
  int l32  = lane & 31;      // 8B chunk within the row (4 features)
  int beg = offs[node], d = cnt[node];
  if (d == 0){
    if (half == 0){
      uint2 z = {0u, 0u};
      *(uint2*)(agg + (size_t)node * HID + l32 * 4) = z;
    }
    return;
  }
  const int* __restrict__ cp = csr + beg;
  float s0 = 0.f, s1 = 0.f, s2 = 0.f, s3 = 0.f;
  int i = 0;
  // unmasked main loop: full groups of 16 edges
  for (; i + 16 <= d; i += 16){
    int idx[8];
    #pragma unroll
    for (int u = 0; u < 8; u++) idx[u] = cp[i + 2 * u + half];
    uint2 v[8];
    #pragma unroll
    for (int u = 0; u < 8; u++)
      v[u] = *(const uint2*)(x + (size_t)idx[u] * HID + l32 * 4);
    #pragma unroll
    for (int u = 0; u < 8; u++){
      s0 += bf2f((ushort)v[u].x);
      s1 += bf2f((ushort)(v[u].x >> 16));
      s2 += bf2f((ushort)v[u].y);
      s3 += bf2f((ushort)(v[u].y >> 16));
    }
  }
  // masked tail
  if (i < d){
    int idx[8]; float w[8];
    #pragma unroll
    for (int u = 0; u < 8; u++){
      int pos = i + 2 * u + half;
      bool ok = pos < d;
      pos = ok ? pos : d - 1;
      idx[u] = cp[pos];
      w[u] = ok ? 1.f : 0.f;
    }
    uint2 v[8];
    #pragma unroll
    for (int u = 0; u < 8; u++)
      v[u] = *(const uint2*)(x + (size_t)idx[u] * HID + l32 * 4);
    #pragma unroll
    for (int u = 0; u < 8; u++){
      s0 = fmaf(w[u], bf2f((ushort)v[u].x), s0);
      s1 = fmaf(w[u], bf2f((ushort)(v[u].x >> 16)), s1);
      s2 = fmaf(w[u], bf2f((ushort)v[u].y), s2);
      s3 = fmaf(w[u], bf2f((ushort)(v[u].y >> 16)), s3);
    }
  }
  // combine the two halves
  s0 += __shfl_xor(s0, 32, 64);
  s1 += __shfl_xor(s1, 32, 64);
  s2 += __shfl_xor(s2, 32, 64);
  s3 += __shfl_xor(s3, 32, 64);
  if (half == 0){
    float inv = 1.0f / fmaxf((float)d, 1.0f);
    uint2 o;
    o.x = (uint)f2bf(s0 * inv) | ((uint)f2bf(s1 * inv) << 16);
    o.y = (uint)f2bf(s2 * inv) | ((uint)f2bf(s3 * inv) << 16);
    *(uint2*)(agg + (size_t)node * HID + l32 * 4) = o;
  }
}

// ---------------- fused dual-GEMM + bias + LN + ReLU + residual ----------------
// Weights staged once per block; barrier-free grid-stride tile loop.
template<int HAS_RES>
__global__ __launch_bounds__(256, 2) void k_layer(
    const ushort* __restrict__ agg, const ushort* __restrict__ xin,
    const ushort* __restrict__ Wf,     // [kt4][mat2][jt8][lane64][8] bf16 (col-permuted)
    const float* __restrict__ bl, const float* __restrict__ gamma,
    const float* __restrict__ beta,
    ushort* __restrict__ xout, int N, int nTiles){
  __shared__ ushort sB[32768];         // 64KB: full layer weights
  int tid = threadIdx.x;
  int wv = tid >> 6, lane = tid & 63;
  int quad = lane >> 4, l16 = lane & 15;

  // one-time weight stage: 4096 chunks of 16B
  #pragma unroll
  for (int i = 0; i < 16; i++){
    int c = i * 256 + tid;
    *(bf16x8*)(sB + c * 8) = load8(Wf + c * 8);
  }
  __syncthreads();

  // per-thread epilogue constants: 8 contiguous cols starting at l16*8
  float4 bi0 = *(const float4*)(bl + l16 * 8);
  float4 bi1 = *(const float4*)(bl + l16 * 8 + 4);
  float4 g0 = *(const float4*)(gamma + l16 * 8);
  float4 g1 = *(const float4*)(gamma + l16 * 8 + 4);
  float4 be0 = *(const float4*)(beta + l16 * 8);
  float4 be1 = *(const float4*)(beta + l16 * 8 + 4);
  float gg[8] = {g0.x, g0.y, g0.z, g0.w, g1.x, g1.y, g1.z, g1.w};
  float bb[8] = {be0.x, be0.y, be0.z, be0.w, be1.x, be1.y, be1.z, be1.w};
  float bia[8] = {bi0.x, bi0.y, bi0.z, bi0.w, bi1.x, bi1.y, bi1.z, bi1.w};

  for (int tile = blockIdx.x; tile < nTiles; tile += gridDim.x){
    int rowbase = tile * 128 + wv * 32;
    int r0 = rowbase + l16;      if (r0 >= N) r0 = N - 1;
    int r1 = rowbase + 16 + l16; if (r1 >= N) r1 = N - 1;

    // issue all 16 A-fragment loads up front
    bf16x8 aL0[4], aL1[4], aR0[4], aR1[4];
    #pragma unroll
    for (int kt = 0; kt < 4; kt++){
      int ao = kt * 32 + quad * 8;
      aL0[kt] = load8(agg + (size_t)r0 * HID + ao);
      aL1[kt] = load8(agg + (size_t)r1 * HID + ao);
      aR0[kt] = load8(xin + (size_t)r0 * HID + ao);
      aR1[kt] = load8(xin + (size_t)r1 * HID + ao);
    }

    f32x4 acc[2][8];
    #pragma unroll
    for (int jt = 0; jt < 8; jt++){
      float b = bia[jt];
      f32x4 c = {b, b, b, b};
      acc[0][jt] = c; acc[1][jt] = c;
    }

    #pragma unroll
    for (int kt = 0; kt < 4; kt++){
      #pragma unroll
      for (int jt = 0; jt < 8; jt++){
        bf16x8 bL = load8(sB + ((kt * 16 + jt) * 64 + lane) * 8);
        bf16x8 bR = load8(sB + ((kt * 16 + 8 + jt) * 64 + lane) * 8);
        acc[0][jt] = __builtin_amdgcn_mfma_f32_16x16x32_bf16(aL0[kt], bL, acc[0][jt], 0, 0, 0);
        acc[1][jt] = __builtin_amdgcn_mfma_f32_16x16x32_bf16(aL1[kt], bL, acc[1][jt], 0, 0, 0);
        acc[0][jt] = __builtin_amdgcn_mfma_f32_16x16x32_bf16(aR0[kt], bR, acc[0][jt], 0, 0, 0);
        acc[1][jt] = __builtin_amdgcn_mfma_f32_16x16x32_bf16(aR1[kt], bR, acc[1][jt], 0, 0, 0);
      }
    }

    #pragma unroll
    for (int rt = 0; rt < 2; rt++){
      float s1[4] = {0,0,0,0}, s2[4] = {0,0,0,0};
      #pragma unroll
      for (int jt = 0; jt < 8; jt++){
        #pragma unroll
        for (int r = 0; r < 4; r++){ float v = acc[rt][jt][r]; s1[r] += v; s2[r] += v * v; }
      }
      #pragma unroll
      for (int m = 1; m < 16; m <<= 1){
        #pragma unroll
        for (int r = 0; r < 4; r++){
          s1[r] += __shfl_xor(s1[r], m, 64);
          s2[r] += __shfl_xor(s2[r], m, 64);
        }
      }
      #pragma unroll
      for (int r = 0; r < 4; r++){
        float mu = s1[r] * (1.f / 128.f);
        float var = s2[r] * (1.f / 128.f) - mu * mu;
        float rs = rsqrtf(var + 1e-5f);
        int row = rowbase + rt * 16 + quad * 4 + r;
        int rowc = row < N ? row : N - 1;
        // residual: plain uint4 load, ushort bit-extract
        uint rw[4] = {0u, 0u, 0u, 0u};
        if (HAS_RES){
          uint4 rv = *(const uint4*)(xin + (size_t)rowc * HID + l16 * 8);
          rw[0] = rv.x; rw[1] = rv.y; rw[2] = rv.z; rw[3] = rv.w;
        }
        uint ow[4];
        #pragma unroll
        for (int p = 0; p < 4; p++){
          float v0 = (acc[rt][2 * p][r] - mu) * rs * gg[2 * p] + bb[2 * p];
          float v1 = (acc[rt][2 * p + 1][r] - mu) * rs * gg[2 * p + 1] + bb[2 * p + 1];
          v0 = fmaxf(v0, 0.f);
          v1 = fmaxf(v1, 0.f);
          if (HAS_RES){
            v0 += bf2f((ushort)(rw[p] & 0xffffu));
            v1 += bf2f((ushort)(rw[p] >> 16));
          }
          ow[p] = (uint)f2bf(v0) | ((uint)f2bf(v1) << 16);
        }
        uint4 o;
        o.x = ow[0]; o.y = ow[1]; o.z = ow[2]; o.w = ow[3];
        if (row < N)
          *(uint4*)(xout + (size_t)row * HID + l16 * 8) = o;
      }
    }
  }
}

// ---------------- JK: out = [emb,x1,x2,x3] @ jkW^T + jkb  (out f32) ----------------
// v3: ALL 128KB of jk weights staged into LDS once per block (512 threads,
// 1 block/CU), then barrier-free grid-stride over 256-row tiles. Per source:
// 8 prefetched A-loads -> 64 MFMAs; 4 independent source groups pipeline freely.
__global__ __launch_bounds__(512, 2) void k_jk(
    const ushort* __restrict__ emb, const ushort* __restrict__ x1,
    const ushort* __restrict__ x2, const ushort* __restrict__ x3,
    const ushort* __restrict__ Wf,   // [kt16][jt8][lane64][8] bf16 (col-permuted)
    const float* __restrict__ jkb, float* __restrict__ out, int N, int nTiles){
  __shared__ ushort sB[65536];       // 128KB: ALL jk weights
  int tid = threadIdx.x;
  int wv = tid >> 6, lane = tid & 63;
  int quad = lane >> 4, l16 = lane & 15;

  // one-time weight stage: 8192 chunks of 16B, 512 threads, 16 iters
  #pragma unroll
  for (int i = 0; i < 16; i++){
    int c = i * 512 + tid;
    *(bf16x8*)(sB + c * 8) = load8(Wf + c * 8);
  }
  __syncthreads();

  float4 jb0 = *(const float4*)(jkb + l16 * 4);
  float4 jb1 = *(const float4*)(jkb + 64 + l16 * 4);
  float bia[8] = {jb0.x, jb0.y, jb0.z, jb0.w, jb1.x, jb1.y, jb1.z, jb1.w};

  const ushort* srcs[4] = {emb, x1, x2, x3};

  for (int tile = blockIdx.x; tile < nTiles; tile += gridDim.x){
    int rowbase = tile * 256 + wv * 32;     // 8 waves x 32 rows = 256-row tile
    int r0 = rowbase + l16;      if (r0 >= N) r0 = N - 1;
    int r1 = rowbase + 16 + l16; if (r1 >= N) r1 = N - 1;

    f32x4 acc[2][8];
    #pragma unroll
    for (int jt = 0; jt < 8; jt++){
      float b = bia[jt];
      f32x4 c = {b, b, b, b};
      acc[0][jt] = c; acc[1][jt] = c;
    }

    #pragma unroll
    for (int s = 0; s < 4; s++){
      const ushort* sp = srcs[s];
      bf16x8 a0[4], a1[4];
      #pragma unroll
      for (int kt = 0; kt < 4; kt++){
        int ao = kt * 32 + quad * 8;
        a0[kt] = load8(sp + (size_t)r0 * HID + ao);
        a1[kt] = load8(sp + (size_t)r1 * HID + ao);
      }
      #pragma unroll
      for (int kt = 0; kt < 4; kt++){
        int ktg = s * 4 + kt;
        #pragma unroll
        for (int jt = 0; jt < 8; jt++){
          bf16x8 bW = load8(sB + ((ktg * 8 + jt) * 64 + lane) * 8);
          acc[0][jt] = __builtin_amdgcn_mfma_f32_16x16x32_bf16(a0[kt], bW, acc[0][jt], 0, 0, 0);
          acc[1][jt] = __builtin_amdgcn_mfma_f32_16x16x32_bf16(a1[kt], bW, acc[1][jt], 0, 0, 0);
        }
      }
    }

    #pragma unroll
    for (int rt = 0; rt < 2; rt++){
      #pragma unroll
      for (int r = 0; r < 4; r++){
        int row = rowbase + rt * 16 + quad * 4 + r;
        if (row < N){
          f32x4 v0 = {acc[rt][0][r], acc[rt][1][r], acc[rt][2][r], acc[rt][3][r]};
          f32x4 v1 = {acc[rt][4][r], acc[rt][5][r], acc[rt][6][r], acc[rt][7][r]};
          *(f32x4*)(out + (size_t)row * HID + l16 * 4) = v0;
          *(f32x4*)(out + (size_t)row * HID + 64 + l16 * 4) = v1;
        }
      }
    }
  }
}

extern "C" void kernel_launch(void* const* d_in, const int* in_sizes, int n_in,
                              void* d_out, int out_size, void* d_ws, size_t ws_size,
                              hipStream_t stream){
  const float* emb   = (const float*)d_in[0];
  const float* Wl    = (const float*)d_in[1];
  const float* bl    = (const float*)d_in[2];
  const float* Wr    = (const float*)d_in[3];
  const float* gamma = (const float*)d_in[4];
  const float* beta  = (const float*)d_in[5];
  const float* jkW   = (const float*)d_in[6];
  const float* jkb   = (const float*)d_in[7];
  const int*   eidx  = (const int*)d_in[8];
  int N = in_sizes[0] / HID;
  int E = in_sizes[8] / 2;
  const int* src = eidx;
  const int* dst = eidx + E;
  float* out = (float*)d_out;

  int NB = (N + 127) >> BSHIFT;        // coarse buckets of 128 nodes
  int es = (E + NBLK - 1) / NBLK;      // edges per slice block

  // workspace carve (256B aligned)
  char* w = (char*)d_ws;
  auto carve = [&](size_t bytes) -> char* {
    char* p = w; w += (bytes + 255) & ~(size_t)255; return p;
  };
  int Npad = ((N + 255) / 256) * 256;
  int* rowcnt   = (int*)carve((size_t)NBLK * NB * 4);
  int* bbase    = (int*)carve((size_t)(NB + 1) * 4);
  uint* binned  = (uint*)carve((size_t)E * 4);
  int* cnt      = (int*)carve((size_t)N * 4);
  int* offs     = (int*)carve((size_t)N * 4);
  int* csr      = (int*)carve((size_t)E * 4);
  ushort* Wfrag = (ushort*)carve((size_t)3 * 32768 * 2);
  ushort* jkWf  = (ushort*)carve((size_t)65536 * 2);
  ushort* embbf = (ushort*)carve((size_t)Npad * HID * 2);
  ushort* agg   = (ushort*)carve((size_t)Npad * HID * 2);
  ushort* x1    = (ushort*)carve((size_t)Npad * HID * 2);
  ushort* x2    = (ushort*)carve((size_t)Npad * HID * 2);
  ushort* x3    = (ushort*)carve((size_t)Npad * HID * 2);

  // weight transforms + emb cast
  int nEmb = N * HID;
  k_cvtw<<<(3 * 32768 + 255) / 256, 256, 0, stream>>>(Wl, Wr, Wfrag, 3 * 32768);
  k_cvtjk<<<65536 / 256, 256, 0, stream>>>(jkW, jkWf);
  k_cvt<<<(nEmb + 255) / 256, 256, 0, stream>>>(emb, embbf, nEmb);

  // deterministic two-level CSR build
  k_count<<<NBLK, 1024, 0, stream>>>(dst, rowcnt, E, NB, es);
  k_colscan<<<1, 1024, 0, stream>>>(rowcnt, bbase, NB, NBLK);
  k_place<<<NBLK, 1024, 0, stream>>>(src, dst, rowcnt, binned, E, NB, es);
  k_bpass<<<NB, 256, 0, stream>>>(binned, bbase, csr, offs, cnt, N);

  int aggBlocks = (N + 3) / 4;
  int nTiles = (N + 127) / 128;
  int gemmGrid = nTiles < 512 ? nTiles : 512;   // 2 blocks/CU co-resident
  int nTilesJK = (N + 255) / 256;
  int jkGrid = nTilesJK < 256 ? nTilesJK : 256; // 1 block/CU (128KB LDS)

  // layer 0 (no residual)
  k_aggregate<<<aggBlocks, 256, 0, stream>>>(embbf, csr, offs, cnt, agg, N);
  k_layer<0><<<gemmGrid, 256, 0, stream>>>(agg, embbf, Wfrag, bl, gamma, beta, x1, N, nTiles);
  // layer 1
  k_aggregate<<<aggBlocks, 256, 0, stream>>>(x1, csr, offs, cnt, agg, N);
  k_layer<1><<<gemmGrid, 256, 0, stream>>>(agg, x1, Wfrag + 32768, bl + HID,
                                           gamma + HID, beta + HID, x2, N, nTiles);
  // layer 2
  k_aggregate<<<aggBlocks, 256, 0, stream>>>(x2, csr, offs, cnt, agg, N);
  k_layer<1><<<gemmGrid, 256, 0, stream>>>(agg, x2, Wfrag + 2 * 32768, bl + 2 * HID,
                                           gamma + 2 * HID, beta + 2 * HID, x3, N, nTiles);
  // jumping knowledge projection
  k_jk<<<jkGrid, 512, 0, stream>>>(embbf, x1, x2, x3, jkWf, jkb, out, N, nTilesJK);
}

// Round 5
// 542.401 us; speedup vs baseline: 1.3880x; 1.3880x over previous
//
#include <hip/hip_runtime.h>
#include <hip/hip_bf16.h>
#include <stdint.h>

#define HID 128
#define BSHIFT 7
#define NBLK 64      // edge-slice blocks for count/place

typedef __attribute__((ext_vector_type(8))) __bf16 bf16x8;
typedef __attribute__((ext_vector_type(4))) float f32x4;

static __device__ __forceinline__ float bf2f(ushort h){
  union { uint u; float f; } c; c.u = ((uint)h) << 16; return c.f;
}
static __device__ __forceinline__ ushort f2bf(float f){
  union { float f; uint u; } c; c.f = f;
  uint u = c.u;
  return (ushort)((u + 0x7fffu + ((u >> 16) & 1u)) >> 16);
}
static __device__ __forceinline__ bf16x8 load8(const ushort* p){
  return *(const bf16x8*)p;
}

// ---------------- f32 -> bf16 convert (emb) ----------------
__global__ void k_cvt(const float* __restrict__ in, ushort* __restrict__ out, int n){
  int i = blockIdx.x * 256 + threadIdx.x;
  if (i < n) out[i] = f2bf(in[i]);
}

// ---- layer weights f32 -> bf16 frag-major: [layer][kt4][mat2][jt8][lane64][e8] ----
// Column permutation: C-tile jt, lane l16 -> global out col = l16*8 + jt, so each
// thread's 8 jt-accumulators hold 8 CONTIGUOUS output columns (dense 16B stores).
__global__ void k_cvtw(const float* __restrict__ Wl, const float* __restrict__ Wr,
                       ushort* __restrict__ outF, int total){
  int o = blockIdx.x * 256 + threadIdx.x;
  if (o >= total) return;
  int layer = o >> 15;
  int r = o & 32767;
  int e    = r & 7;
  int lane = (r >> 3) & 63;
  int jt   = (r >> 9) & 7;
  int mat  = (r >> 12) & 1;
  int kt   = r >> 13;
  int l16 = lane & 15, quad = lane >> 4;
  int j = l16 * 8 + jt;               // permuted output column
  int k = kt * 32 + quad * 8 + e;
  const float* W = mat ? Wr : Wl;
  outF[o] = f2bf(W[layer * 16384 + j * 128 + k]);
}

// ---- jk weights f32 -> bf16 frag-major: [kt16][jt8][lane64][e8] ----
// f32 output: col = l16*4 + (jt&3) + (jt>>2)*64 -> each thread holds 2 groups of
// 4 contiguous f32 cols (two dense dwordx4 stores per row).
__global__ void k_cvtjk(const float* __restrict__ jkW, ushort* __restrict__ outF){
  int o = blockIdx.x * 256 + threadIdx.x;   // total 65536
  int e    = o & 7;
  int lane = (o >> 3) & 63;
  int jt   = (o >> 9) & 7;
  int kt   = o >> 12;
  int l16 = lane & 15, quad = lane >> 4;
  int j = l16 * 4 + (jt & 3) + (jt >> 2) * 64;   // permuted output column
  int k = kt * 32 + quad * 8 + e;
  outF[o] = f2bf(jkW[j * 512 + k]);
}

// ================ deterministic two-level CSR build (no global atomics) ================
__global__ __launch_bounds__(1024) void k_count(
    const int* __restrict__ dst, int* __restrict__ rowcnt, int E, int NB, int es){
  __shared__ int h[1024];
  int blk = blockIdx.x;
  for (int i = threadIdx.x; i < NB; i += 1024) h[i] = 0;
  __syncthreads();
  int e0 = blk * es, e1 = min(e0 + es, E);
  for (int e = e0 + threadIdx.x; e < e1; e += 1024)
    atomicAdd(&h[dst[e] >> BSHIFT], 1);
  __syncthreads();
  for (int i = threadIdx.x; i < NB; i += 1024)
    rowcnt[blk * NB + i] = h[i];
}

__global__ __launch_bounds__(1024) void k_colscan(
    int* __restrict__ rowcnt, int* __restrict__ bbase, int NB, int nblk){
  int b = threadIdx.x;
  int total = 0;
  if (b < NB)
    for (int r = 0; r < nblk; r++) total += rowcnt[r * NB + b];
  int lane = b & 63, w = b >> 6;
  int x = total;
  #pragma unroll
  for (int d = 1; d < 64; d <<= 1){ int y = __shfl_up(x, d, 64); if (lane >= d) x += y; }
  __shared__ int tmp[16];
  if (lane == 63) tmp[w] = x;
  __syncthreads();
  if (b < 64){
    int s = (lane < 16) ? tmp[lane] : 0;
    #pragma unroll
    for (int d = 1; d < 16; d <<= 1){ int y = __shfl_up(s, d, 64); if (lane >= d) s += y; }
    if (lane < 16) tmp[lane] = s;
  }
  __syncthreads();
  int base = ((w > 0) ? tmp[w - 1] : 0) + x - total;  // exclusive
  if (b < NB){
    bbase[b] = base;
    int acc = base;
    for (int r = 0; r < nblk; r++){
      int v = rowcnt[r * NB + b];
      rowcnt[r * NB + b] = acc;
      acc += v;
    }
    if (b == NB - 1) bbase[NB] = acc;
  }
}

__global__ __launch_bounds__(1024) void k_place(
    const int* __restrict__ src, const int* __restrict__ dst,
    const int* __restrict__ rowcnt, uint* __restrict__ binned, int E, int NB, int es){
  __shared__ int cur[1024];
  int blk = blockIdx.x;
  for (int i = threadIdx.x; i < NB; i += 1024) cur[i] = rowcnt[blk * NB + i];
  __syncthreads();
  int e0 = blk * es, e1 = min(e0 + es, E);
  for (int e = e0 + threadIdx.x; e < e1; e += 1024){
    int d = dst[e];
    int b = d >> BSHIFT;
    int pos = atomicAdd(&cur[b], 1);
    binned[pos] = ((uint)src[e] << BSHIFT) | (uint)(d & 127);
  }
}

__global__ __launch_bounds__(256) void k_bpass(
    const uint* __restrict__ binned, const int* __restrict__ bbase,
    int* __restrict__ csr, int* __restrict__ offs, int* __restrict__ cnt, int N){
  int b = blockIdx.x;
  int n0 = b << BSHIFT;
  int tid = threadIdx.x;
  __shared__ int lcnt[128], loffs[128];
  if (tid < 128) lcnt[tid] = 0;
  __syncthreads();
  int base = bbase[b];
  int m = bbase[b + 1] - base;
  const uint* bp = binned + base;
  uint vv[12]; int slot[12];
  #pragma unroll
  for (int u = 0; u < 12; u++){
    int i = tid + u * 256;
    if (i < m){
      uint v = bp[i];
      vv[u] = v;
      slot[u] = atomicAdd(&lcnt[v & 127], 1);
    }
  }
  __syncthreads();
  if (tid < 64){
    int a0 = lcnt[tid * 2], a1 = lcnt[tid * 2 + 1];
    int s = a0 + a1;
    int x = s;
    #pragma unroll
    for (int d = 1; d < 64; d <<= 1){ int y = __shfl_up(x, d, 64); if (tid >= d) x += y; }
    int excl = x - s;
    loffs[tid * 2] = excl;
    loffs[tid * 2 + 1] = excl + a0;
  }
  __syncthreads();
  if (tid < 128 && n0 + tid < N){
    cnt[n0 + tid] = lcnt[tid];
    offs[n0 + tid] = base + loffs[tid];
  }
  #pragma unroll
  for (int u = 0; u < 12; u++){
    int i = tid + u * 256;
    if (i < m){
      uint v = vv[u];
      csr[base + loffs[v & 127] + slot[u]] = (int)(v >> BSHIFT);
    }
  }
}

// ---------------- scatter-mean aggregation ----------------
__global__ __launch_bounds__(256) void k_aggregate(
    const ushort* __restrict__ x, const int* __restrict__ csr,
    const int* __restrict__ offs, const int* __restrict__ cnt,
    ushort* __restrict__ agg, int N){
  int node = blockIdx.x * 4 + (threadIdx.x >> 6);
  int lane = threadIdx.x & 63;
  if (node >= N) return;
  int half = lane >> 5;      // which edge of the pair
  int l32  = lane & 31;      // 8B chunk within the row (4 features)
  int beg = offs[node], d = cnt[node];
  if (d == 0){
    if (half == 0){
      uint2 z = {0u, 0u};
      *(uint2*)(agg + (size_t)node * HID + l32 * 4) = z;
    }
    return;
  }
  const int* __restrict__ cp = csr + beg;
  float s0 = 0.f, s1 = 0.f, s2 = 0.f, s3 = 0.f;
  int i = 0;
  // unmasked main loop: full groups of 16 edges
  for (; i + 16 <= d; i += 16){
    int idx[8];
    #pragma unroll
    for (int u = 0; u < 8; u++) idx[u] = cp[i + 2 * u + half];
    uint2 v[8];
    #pragma unroll
    for (int u = 0; u < 8; u++)
      v[u] = *(const uint2*)(x + (size_t)idx[u] * HID + l32 * 4);
    #pragma unroll
    for (int u = 0; u < 8; u++){
      s0 += bf2f((ushort)v[u].x);
      s1 += bf2f((ushort)(v[u].x >> 16));
      s2 += bf2f((ushort)v[u].y);
      s3 += bf2f((ushort)(v[u].y >> 16));
    }
  }
  // masked tail
  if (i < d){
    int idx[8]; float w[8];
    #pragma unroll
    for (int u = 0; u < 8; u++){
      int pos = i + 2 * u + half;
      bool ok = pos < d;
      pos = ok ? pos : d - 1;
      idx[u] = cp[pos];
      w[u] = ok ? 1.f : 0.f;
    }
    uint2 v[8];
    #pragma unroll
    for (int u = 0; u < 8; u++)
      v[u] = *(const uint2*)(x + (size_t)idx[u] * HID + l32 * 4);
    #pragma unroll
    for (int u = 0; u < 8; u++){
      s0 = fmaf(w[u], bf2f((ushort)v[u].x), s0);
      s1 = fmaf(w[u], bf2f((ushort)(v[u].x >> 16)), s1);
      s2 = fmaf(w[u], bf2f((ushort)v[u].y), s2);
      s3 = fmaf(w[u], bf2f((ushort)(v[u].y >> 16)), s3);
    }
  }
  // combine the two halves
  s0 += __shfl_xor(s0, 32, 64);
  s1 += __shfl_xor(s1, 32, 64);
  s2 += __shfl_xor(s2, 32, 64);
  s3 += __shfl_xor(s3, 32, 64);
  if (half == 0){
    float inv = 1.0f / fmaxf((float)d, 1.0f);
    uint2 o;
    o.x = (uint)f2bf(s0 * inv) | ((uint)f2bf(s1 * inv) << 16);
    o.y = (uint)f2bf(s2 * inv) | ((uint)f2bf(s3 * inv) << 16);
    *(uint2*)(agg + (size_t)node * HID + l32 * 4) = o;
  }
}

// ---------------- fused dual-GEMM + bias + LN + ReLU + residual ----------------
// v4: NO LDS, NO barriers. One 128-row tile per block (the clean-traffic
// schedule, per R0 vs R1-R4 counters). B-fragments read directly from global:
// the 64-128KB weight region is L2/L3-resident and every wave's frag load is a
// fully-coalesced 1KB read broadcast across blocks. All-pipe-idle latency in R0
// came from 8 vmcnt(0)-draining barriers/tile -- now zero barriers, and
// __launch_bounds__(256,3) keeps >=12 barrier-free waves/CU.
template<int HAS_RES>
__global__ __launch_bounds__(256, 3) void k_layer(
    const ushort* __restrict__ agg, const ushort* __restrict__ xin,
    const ushort* __restrict__ Wf,     // [kt4][mat2][jt8][lane64][8] bf16 (col-permuted)
    const float* __restrict__ bl, const float* __restrict__ gamma,
    const float* __restrict__ beta,
    ushort* __restrict__ xout, int N){
  int tid = threadIdx.x;
  int wv = tid >> 6, lane = tid & 63;
  int quad = lane >> 4, l16 = lane & 15;
  int rowbase = blockIdx.x * 128 + wv * 32;
  int r0 = rowbase + l16;      if (r0 >= N) r0 = N - 1;
  int r1 = rowbase + 16 + l16; if (r1 >= N) r1 = N - 1;

  // issue all 16 A-fragment loads up front (independent, in flight together)
  bf16x8 aL0[4], aL1[4], aR0[4], aR1[4];
  #pragma unroll
  for (int kt = 0; kt < 4; kt++){
    int ao = kt * 32 + quad * 8;
    aL0[kt] = load8(agg + (size_t)r0 * HID + ao);
    aL1[kt] = load8(agg + (size_t)r1 * HID + ao);
    aR0[kt] = load8(xin + (size_t)r0 * HID + ao);
    aR1[kt] = load8(xin + (size_t)r1 * HID + ao);
  }

  // per-thread epilogue constants: 8 contiguous cols starting at l16*8
  float4 bi0 = *(const float4*)(bl + l16 * 8);
  float4 bi1 = *(const float4*)(bl + l16 * 8 + 4);
  float4 g0 = *(const float4*)(gamma + l16 * 8);
  float4 g1 = *(const float4*)(gamma + l16 * 8 + 4);
  float4 be0 = *(const float4*)(beta + l16 * 8);
  float4 be1 = *(const float4*)(beta + l16 * 8 + 4);
  float gg[8] = {g0.x, g0.y, g0.z, g0.w, g1.x, g1.y, g1.z, g1.w};
  float bb[8] = {be0.x, be0.y, be0.z, be0.w, be1.x, be1.y, be1.z, be1.w};
  float bia[8] = {bi0.x, bi0.y, bi0.z, bi0.w, bi1.x, bi1.y, bi1.z, bi1.w};

  f32x4 acc[2][8];
  #pragma unroll
  for (int jt = 0; jt < 8; jt++){
    float b = bia[jt];
    f32x4 c = {b, b, b, b};
    acc[0][jt] = c; acc[1][jt] = c;
  }

  #pragma unroll
  for (int kt = 0; kt < 4; kt++){
    #pragma unroll
    for (int jt = 0; jt < 8; jt++){
      bf16x8 bL = load8(Wf + ((kt * 16 + jt) * 64 + lane) * 8);
      bf16x8 bR = load8(Wf + ((kt * 16 + 8 + jt) * 64 + lane) * 8);
      acc[0][jt] = __builtin_amdgcn_mfma_f32_16x16x32_bf16(aL0[kt], bL, acc[0][jt], 0, 0, 0);
      acc[1][jt] = __builtin_amdgcn_mfma_f32_16x16x32_bf16(aL1[kt], bL, acc[1][jt], 0, 0, 0);
      acc[0][jt] = __builtin_amdgcn_mfma_f32_16x16x32_bf16(aR0[kt], bR, acc[0][jt], 0, 0, 0);
      acc[1][jt] = __builtin_amdgcn_mfma_f32_16x16x32_bf16(aR1[kt], bR, acc[1][jt], 0, 0, 0);
    }
  }

  #pragma unroll
  for (int rt = 0; rt < 2; rt++){
    float s1[4] = {0,0,0,0}, s2[4] = {0,0,0,0};
    #pragma unroll
    for (int jt = 0; jt < 8; jt++){
      #pragma unroll
      for (int r = 0; r < 4; r++){ float v = acc[rt][jt][r]; s1[r] += v; s2[r] += v * v; }
    }
    #pragma unroll
    for (int m = 1; m < 16; m <<= 1){
      #pragma unroll
      for (int r = 0; r < 4; r++){
        s1[r] += __shfl_xor(s1[r], m, 64);
        s2[r] += __shfl_xor(s2[r], m, 64);
      }
    }
    #pragma unroll
    for (int r = 0; r < 4; r++){
      float mu = s1[r] * (1.f / 128.f);
      float var = s2[r] * (1.f / 128.f) - mu * mu;
      float rs = rsqrtf(var + 1e-5f);
      int row = rowbase + rt * 16 + quad * 4 + r;
      int rowc = row < N ? row : N - 1;
      // residual: plain uint4 load, ushort bit-extract
      uint rw[4] = {0u, 0u, 0u, 0u};
      if (HAS_RES){
        uint4 rv = *(const uint4*)(xin + (size_t)rowc * HID + l16 * 8);
        rw[0] = rv.x; rw[1] = rv.y; rw[2] = rv.z; rw[3] = rv.w;
      }
      uint ow[4];
      #pragma unroll
      for (int p = 0; p < 4; p++){
        float v0 = (acc[rt][2 * p][r] - mu) * rs * gg[2 * p] + bb[2 * p];
        float v1 = (acc[rt][2 * p + 1][r] - mu) * rs * gg[2 * p + 1] + bb[2 * p + 1];
        v0 = fmaxf(v0, 0.f);
        v1 = fmaxf(v1, 0.f);
        if (HAS_RES){
          v0 += bf2f((ushort)(rw[p] & 0xffffu));
          v1 += bf2f((ushort)(rw[p] >> 16));
        }
        ow[p] = (uint)f2bf(v0) | ((uint)f2bf(v1) << 16);
      }
      uint4 o;
      o.x = ow[0]; o.y = ow[1]; o.z = ow[2]; o.w = ow[3];
      if (row < N)
        *(uint4*)(xout + (size_t)row * HID + l16 * 8) = o;
    }
  }
}

// ---------------- JK: out = [emb,x1,x2,x3] @ jkW^T + jkb  (out f32) ----------------
// v4: NO LDS, NO barriers, one 128-row tile per block. B-fragments direct from
// global (128KB, L2/L3-resident). Per source: 8 A-loads then 32 B-loads+MFMAs.
__global__ __launch_bounds__(256, 3) void k_jk(
    const ushort* __restrict__ emb, const ushort* __restrict__ x1,
    const ushort* __restrict__ x2, const ushort* __restrict__ x3,
    const ushort* __restrict__ Wf,   // [kt16][jt8][lane64][8] bf16 (col-permuted)
    const float* __restrict__ jkb, float* __restrict__ out, int N){
  int tid = threadIdx.x;
  int wv = tid >> 6, lane = tid & 63;
  int quad = lane >> 4, l16 = lane & 15;
  int rowbase = blockIdx.x * 128 + wv * 32;
  int r0 = rowbase + l16;      if (r0 >= N) r0 = N - 1;
  int r1 = rowbase + 16 + l16; if (r1 >= N) r1 = N - 1;

  float4 jb0 = *(const float4*)(jkb + l16 * 4);
  float4 jb1 = *(const float4*)(jkb + 64 + l16 * 4);
  float bia[8] = {jb0.x, jb0.y, jb0.z, jb0.w, jb1.x, jb1.y, jb1.z, jb1.w};

  f32x4 acc[2][8];
  #pragma unroll
  for (int jt = 0; jt < 8; jt++){
    float b = bia[jt];
    f32x4 c = {b, b, b, b};
    acc[0][jt] = c; acc[1][jt] = c;
  }

  const ushort* srcs[4] = {emb, x1, x2, x3};
  #pragma unroll
  for (int s = 0; s < 4; s++){
    const ushort* sp = srcs[s];
    bf16x8 a0[4], a1[4];
    #pragma unroll
    for (int kt = 0; kt < 4; kt++){
      int ao = kt * 32 + quad * 8;
      a0[kt] = load8(sp + (size_t)r0 * HID + ao);
      a1[kt] = load8(sp + (size_t)r1 * HID + ao);
    }
    #pragma unroll
    for (int kt = 0; kt < 4; kt++){
      int ktg = s * 4 + kt;
      #pragma unroll
      for (int jt = 0; jt < 8; jt++){
        bf16x8 bW = load8(Wf + ((ktg * 8 + jt) * 64 + lane) * 8);
        acc[0][jt] = __builtin_amdgcn_mfma_f32_16x16x32_bf16(a0[kt], bW, acc[0][jt], 0, 0, 0);
        acc[1][jt] = __builtin_amdgcn_mfma_f32_16x16x32_bf16(a1[kt], bW, acc[1][jt], 0, 0, 0);
      }
    }
  }

  #pragma unroll
  for (int rt = 0; rt < 2; rt++){
    #pragma unroll
    for (int r = 0; r < 4; r++){
      int row = rowbase + rt * 16 + quad * 4 + r;
      if (row < N){
        f32x4 v0 = {acc[rt][0][r], acc[rt][1][r], acc[rt][2][r], acc[rt][3][r]};
        f32x4 v1 = {acc[rt][4][r], acc[rt][5][r], acc[rt][6][r], acc[rt][7][r]};
        *(f32x4*)(out + (size_t)row * HID + l16 * 4) = v0;
        *(f32x4*)(out + (size_t)row * HID + 64 + l16 * 4) = v1;
      }
    }
  }
}

extern "C" void kernel_launch(void* const* d_in, const int* in_sizes, int n_in,
                              void* d_out, int out_size, void* d_ws, size_t ws_size,
                              hipStream_t stream){
  const float* emb   = (const float*)d_in[0];
  const float* Wl    = (const float*)d_in[1];
  const float* bl    = (const float*)d_in[2];
  const float* Wr    = (const float*)d_in[3];
  const float* gamma = (const float*)d_in[4];
  const float* beta  = (const float*)d_in[5];
  const float* jkW   = (const float*)d_in[6];
  const float* jkb   = (const float*)d_in[7];
  const int*   eidx  = (const int*)d_in[8];
  int N = in_sizes[0] / HID;
  int E = in_sizes[8] / 2;
  const int* src = eidx;
  const int* dst = eidx + E;
  float* out = (float*)d_out;

  int NB = (N + 127) >> BSHIFT;        // coarse buckets of 128 nodes
  int es = (E + NBLK - 1) / NBLK;      // edges per slice block

  // workspace carve (256B aligned)
  char* w = (char*)d_ws;
  auto carve = [&](size_t bytes) -> char* {
    char* p = w; w += (bytes + 255) & ~(size_t)255; return p;
  };
  int Npad = ((N + 127) / 128) * 128;
  int* rowcnt   = (int*)carve((size_t)NBLK * NB * 4);
  int* bbase    = (int*)carve((size_t)(NB + 1) * 4);
  uint* binned  = (uint*)carve((size_t)E * 4);
  int* cnt      = (int*)carve((size_t)N * 4);
  int* offs     = (int*)carve((size_t)N * 4);
  int* csr      = (int*)carve((size_t)E * 4);
  ushort* Wfrag = (ushort*)carve((size_t)3 * 32768 * 2);
  ushort* jkWf  = (ushort*)carve((size_t)65536 * 2);
  ushort* embbf = (ushort*)carve((size_t)Npad * HID * 2);
  ushort* agg   = (ushort*)carve((size_t)Npad * HID * 2);
  ushort* x1    = (ushort*)carve((size_t)Npad * HID * 2);
  ushort* x2    = (ushort*)carve((size_t)Npad * HID * 2);
  ushort* x3    = (ushort*)carve((size_t)Npad * HID * 2);

  // weight transforms + emb cast
  int nEmb = N * HID;
  k_cvtw<<<(3 * 32768 + 255) / 256, 256, 0, stream>>>(Wl, Wr, Wfrag, 3 * 32768);
  k_cvtjk<<<65536 / 256, 256, 0, stream>>>(jkW, jkWf);
  k_cvt<<<(nEmb + 255) / 256, 256, 0, stream>>>(emb, embbf, nEmb);

  // deterministic two-level CSR build
  k_count<<<NBLK, 1024, 0, stream>>>(dst, rowcnt, E, NB, es);
  k_colscan<<<1, 1024, 0, stream>>>(rowcnt, bbase, NB, NBLK);
  k_place<<<NBLK, 1024, 0, stream>>>(src, dst, rowcnt, binned, E, NB, es);
  k_bpass<<<NB, 256, 0, stream>>>(binned, bbase, csr, offs, cnt, N);

  int aggBlocks = (N + 3) / 4;
  int gemmBlocks = (N + 127) / 128;   // one 128-row tile per block

  // layer 0 (no residual)
  k_aggregate<<<aggBlocks, 256, 0, stream>>>(embbf, csr, offs, cnt, agg, N);
  k_layer<0><<<gemmBlocks, 256, 0, stream>>>(agg, embbf, Wfrag, bl, gamma, beta, x1, N);
  // layer 1
  k_aggregate<<<aggBlocks, 256, 0, stream>>>(x1, csr, offs, cnt, agg, N);
  k_layer<1><<<gemmBlocks, 256, 0, stream>>>(agg, x1, Wfrag + 32768, bl + HID,
                                             gamma + HID, beta + HID, x2, N);
  // layer 2
  k_aggregate<<<aggBlocks, 256, 0, stream>>>(x2, csr, offs, cnt, agg, N);
  k_layer<1><<<gemmBlocks, 256, 0, stream>>>(agg, x2, Wfrag + 2 * 32768, bl + 2 * HID,
                                             gamma + 2 * HID, beta + 2 * HID, x3, N);
  // jumping knowledge projection
  k_jk<<<gemmBlocks, 256, 0, stream>>>(embbf, x1, x2, x3, jkWf, jkb, out, N);
}

// Round 6
// 519.242 us; speedup vs baseline: 1.4499x; 1.0446x over previous
//
#include <hip/hip_runtime.h>
#include <hip/hip_bf16.h>
#include <stdint.h>

#define HID 128
#define BSHIFT 7
#define NBLK 64      // edge-slice blocks for count/place

typedef __attribute__((ext_vector_type(8))) __bf16 bf16x8;
typedef __attribute__((ext_vector_type(4))) float f32x4;
typedef __attribute__((ext_vector_type(2))) float f32x2;

static __device__ __forceinline__ float bf2f(ushort h){
  union { uint u; float f; } c; c.u = ((uint)h) << 16; return c.f;
}
static __device__ __forceinline__ float u2f(uint u){
  union { uint u; float f; } c; c.u = u; return c.f;
}
static __device__ __forceinline__ ushort f2bf(float f){
  union { float f; uint u; } c; c.f = f;
  uint u = c.u;
  return (ushort)((u + 0x7fffu + ((u >> 16) & 1u)) >> 16);
}
static __device__ __forceinline__ bf16x8 load8(const ushort* p){
  return *(const bf16x8*)p;
}

// ---------------- f32 -> bf16 convert (emb) ----------------
__global__ void k_cvt(const float* __restrict__ in, ushort* __restrict__ out, int n){
  int i = blockIdx.x * 256 + threadIdx.x;
  if (i < n) out[i] = f2bf(in[i]);
}

// ---- layer weights f32 -> bf16 frag-major: [layer][kt4][mat2][jt8][lane64][e8] ----
// Column permutation: out col = l16*8 + jt -> dense 16B stores in epilogue.
__global__ void k_cvtw(const float* __restrict__ Wl, const float* __restrict__ Wr,
                       ushort* __restrict__ outF, int total){
  int o = blockIdx.x * 256 + threadIdx.x;
  if (o >= total) return;
  int layer = o >> 15;
  int r = o & 32767;
  int e    = r & 7;
  int lane = (r >> 3) & 63;
  int jt   = (r >> 9) & 7;
  int mat  = (r >> 12) & 1;
  int kt   = r >> 13;
  int l16 = lane & 15, quad = lane >> 4;
  int j = l16 * 8 + jt;               // permuted output column
  int k = kt * 32 + quad * 8 + e;
  const float* W = mat ? Wr : Wl;
  outF[o] = f2bf(W[layer * 16384 + j * 128 + k]);
}

// ---- jk weights f32 -> bf16 frag-major: [kt16][jt8][lane64][e8] ----
// col = l16*4 + (jt&3) + (jt>>2)*64 -> two dense dwordx4 stores per row.
__global__ void k_cvtjk(const float* __restrict__ jkW, ushort* __restrict__ outF){
  int o = blockIdx.x * 256 + threadIdx.x;   // total 65536
  int e    = o & 7;
  int lane = (o >> 3) & 63;
  int jt   = (o >> 9) & 7;
  int kt   = o >> 12;
  int l16 = lane & 15, quad = lane >> 4;
  int j = l16 * 4 + (jt & 3) + (jt >> 2) * 64;   // permuted output column
  int k = kt * 32 + quad * 8 + e;
  outF[o] = f2bf(jkW[j * 512 + k]);
}

// ================ deterministic two-level CSR build (no global atomics) ================
__global__ __launch_bounds__(1024) void k_count(
    const int* __restrict__ dst, int* __restrict__ rowcnt, int E, int NB, int es){
  __shared__ int h[1024];
  int blk = blockIdx.x;
  for (int i = threadIdx.x; i < NB; i += 1024) h[i] = 0;
  __syncthreads();
  int e0 = blk * es, e1 = min(e0 + es, E);
  for (int e = e0 + threadIdx.x; e < e1; e += 1024)
    atomicAdd(&h[dst[e] >> BSHIFT], 1);
  __syncthreads();
  for (int i = threadIdx.x; i < NB; i += 1024)
    rowcnt[blk * NB + i] = h[i];
}

__global__ __launch_bounds__(1024) void k_colscan(
    int* __restrict__ rowcnt, int* __restrict__ bbase, int NB, int nblk){
  int b = threadIdx.x;
  int total = 0;
  if (b < NB)
    for (int r = 0; r < nblk; r++) total += rowcnt[r * NB + b];
  int lane = b & 63, w = b >> 6;
  int x = total;
  #pragma unroll
  for (int d = 1; d < 64; d <<= 1){ int y = __shfl_up(x, d, 64); if (lane >= d) x += y; }
  __shared__ int tmp[16];
  if (lane == 63) tmp[w] = x;
  __syncthreads();
  if (b < 64){
    int s = (lane < 16) ? tmp[lane] : 0;
    #pragma unroll
    for (int d = 1; d < 16; d <<= 1){ int y = __shfl_up(s, d, 64); if (lane >= d) s += y; }
    if (lane < 16) tmp[lane] = s;
  }
  __syncthreads();
  int base = ((w > 0) ? tmp[w - 1] : 0) + x - total;  // exclusive
  if (b < NB){
    bbase[b] = base;
    int acc = base;
    for (int r = 0; r < nblk; r++){
      int v = rowcnt[r * NB + b];
      rowcnt[r * NB + b] = acc;
      acc += v;
    }
    if (b == NB - 1) bbase[NB] = acc;
  }
}

__global__ __launch_bounds__(1024) void k_place(
    const int* __restrict__ src, const int* __restrict__ dst,
    const int* __restrict__ rowcnt, uint* __restrict__ binned, int E, int NB, int es){
  __shared__ int cur[1024];
  int blk = blockIdx.x;
  for (int i = threadIdx.x; i < NB; i += 1024) cur[i] = rowcnt[blk * NB + i];
  __syncthreads();
  int e0 = blk * es, e1 = min(e0 + es, E);
  for (int e = e0 + threadIdx.x; e < e1; e += 1024){
    int d = dst[e];
    int b = d >> BSHIFT;
    int pos = atomicAdd(&cur[b], 1);
    binned[pos] = ((uint)src[e] << BSHIFT) | (uint)(d & 127);
  }
}

__global__ __launch_bounds__(256) void k_bpass(
    const uint* __restrict__ binned, const int* __restrict__ bbase,
    int* __restrict__ csr, int* __restrict__ offs, int* __restrict__ cnt, int N){
  int b = blockIdx.x;
  int n0 = b << BSHIFT;
  int tid = threadIdx.x;
  __shared__ int lcnt[128], loffs[128];
  if (tid < 128) lcnt[tid] = 0;
  __syncthreads();
  int base = bbase[b];
  int m = bbase[b + 1] - base;
  const uint* bp = binned + base;
  uint vv[12]; int slot[12];
  #pragma unroll
  for (int u = 0; u < 12; u++){
    int i = tid + u * 256;
    if (i < m){
      uint v = bp[i];
      vv[u] = v;
      slot[u] = atomicAdd(&lcnt[v & 127], 1);
    }
  }
  __syncthreads();
  if (tid < 64){
    int a0 = lcnt[tid * 2], a1 = lcnt[tid * 2 + 1];
    int s = a0 + a1;
    int x = s;
    #pragma unroll
    for (int d = 1; d < 64; d <<= 1){ int y = __shfl_up(x, d, 64); if (tid >= d) x += y; }
    int excl = x - s;
    loffs[tid * 2] = excl;
    loffs[tid * 2 + 1] = excl + a0;
  }
  __syncthreads();
  if (tid < 128 && n0 + tid < N){
    cnt[n0 + tid] = lcnt[tid];
    offs[n0 + tid] = base + loffs[tid];
  }
  #pragma unroll
  for (int u = 0; u < 12; u++){
    int i = tid + u * 256;
    if (i < m){
      uint v = vv[u];
      csr[base + loffs[v & 127] + slot[u]] = (int)(v >> BSHIFT);
    }
  }
}

// ---------------- scatter-mean aggregation v4 ----------------
// Wave per node. VALU cuts: 32-bit byte-offset addressing (SGPR-base+voffset
// gathers, no 64-bit addc chains), f32x2 packed accumulation (hi-bf16 via AND,
// v_pk_add_f32), tail via value-zeroing cndmask instead of weighted fmaf.
__global__ __launch_bounds__(256) void k_aggregate(
    const ushort* __restrict__ x, const int* __restrict__ csr,
    const int* __restrict__ offs, const int* __restrict__ cnt,
    ushort* __restrict__ agg, int N){
  int node = blockIdx.x * 4 + (threadIdx.x >> 6);
  int lane = threadIdx.x & 63;
  if (node >= N) return;
  int half = lane >> 5;      // which edge of the pair
  int l32  = lane & 31;      // 8B chunk within the row (4 features)
  uint lb  = (uint)(l32 << 3);
  int beg = offs[node], d = cnt[node];
  if (d == 0){
    if (half == 0){
      uint2 z = {0u, 0u};
      *(uint2*)(agg + (size_t)node * HID + l32 * 4) = z;
    }
    return;
  }
  const int* __restrict__ cp = csr + beg;
  const char* __restrict__ xb = (const char*)x;
  f32x2 sx = {0.f, 0.f}, sy = {0.f, 0.f};
  int i = 0;
  // unmasked main loop: full groups of 16 edges
  for (; i + 16 <= d; i += 16){
    uint off[8];
    #pragma unroll
    for (int u = 0; u < 8; u++)
      off[u] = ((uint)cp[i + 2 * u + half] << 8) + lb;
    uint2 v[8];
    #pragma unroll
    for (int u = 0; u < 8; u++)
      v[u] = *(const uint2*)(xb + off[u]);
    #pragma unroll
    for (int u = 0; u < 8; u++){
      f32x2 tx = { u2f(v[u].x << 16), u2f(v[u].x & 0xffff0000u) };
      f32x2 ty = { u2f(v[u].y << 16), u2f(v[u].y & 0xffff0000u) };
      sx += tx; sy += ty;
    }
  }
  // masked tail: clamp index, zero the loaded VALUE (bf2f(0)==+0)
  if (i < d){
    uint off[8]; bool ok[8];
    #pragma unroll
    for (int u = 0; u < 8; u++){
      int pos = i + 2 * u + half;
      ok[u] = pos < d;
      off[u] = ((uint)cp[ok[u] ? pos : d - 1] << 8) + lb;
    }
    uint2 v[8];
    #pragma unroll
    for (int u = 0; u < 8; u++)
      v[u] = *(const uint2*)(xb + off[u]);
    #pragma unroll
    for (int u = 0; u < 8; u++){
      uint ax = ok[u] ? v[u].x : 0u;
      uint ay = ok[u] ? v[u].y : 0u;
      f32x2 tx = { u2f(ax << 16), u2f(ax & 0xffff0000u) };
      f32x2 ty = { u2f(ay << 16), u2f(ay & 0xffff0000u) };
      sx += tx; sy += ty;
    }
  }
  // combine the two halves
  sx.x += __shfl_xor(sx.x, 32, 64);
  sx.y += __shfl_xor(sx.y, 32, 64);
  sy.x += __shfl_xor(sy.x, 32, 64);
  sy.y += __shfl_xor(sy.y, 32, 64);
  if (half == 0){
    float inv = 1.0f / fmaxf((float)d, 1.0f);
    uint2 o;
    o.x = (uint)f2bf(sx.x * inv) | ((uint)f2bf(sx.y * inv) << 16);
    o.y = (uint)f2bf(sy.x * inv) | ((uint)f2bf(sy.y * inv) << 16);
    *(uint2*)(agg + (size_t)node * HID + l32 * 4) = o;
  }
}

// ---------------- fused dual-GEMM + bias + LN + ReLU + residual ----------------
// v5: no LDS, no barriers, one 128-row tile per block. A-fragments loaded
// per-kt with a 1-deep register pipeline (32 live A-regs instead of 64);
// epilogue constants loaded AFTER the MFMA loop. Target <=128 VGPR so
// __launch_bounds__(256,4) gives 16 barrier-free waves/CU (R5 likely sat at
// 8/CU in the >128-VGPR band, which is why it barely beat R0).
template<int HAS_RES>
__global__ __launch_bounds__(256, 4) void k_layer(
    const ushort* __restrict__ agg, const ushort* __restrict__ xin,
    const ushort* __restrict__ Wf,     // [kt4][mat2][jt8][lane64][8] bf16 (col-permuted)
    const float* __restrict__ bl, const float* __restrict__ gamma,
    const float* __restrict__ beta,
    ushort* __restrict__ xout, int N){
  int tid = threadIdx.x;
  int wv = tid >> 6, lane = tid & 63;
  int quad = lane >> 4, l16 = lane & 15;
  int rowbase = blockIdx.x * 128 + wv * 32;
  int r0 = rowbase + l16;      if (r0 >= N) r0 = N - 1;
  int r1 = rowbase + 16 + l16; if (r1 >= N) r1 = N - 1;
  int aq = quad * 8;

  const ushort* pa0 = agg + (size_t)r0 * HID;
  const ushort* pa1 = agg + (size_t)r1 * HID;
  const ushort* px0 = xin + (size_t)r0 * HID;
  const ushort* px1 = xin + (size_t)r1 * HID;

  f32x4 acc[2][8];
  {
    float4 bi0 = *(const float4*)(bl + l16 * 8);
    float4 bi1 = *(const float4*)(bl + l16 * 8 + 4);
    float bia[8] = {bi0.x, bi0.y, bi0.z, bi0.w, bi1.x, bi1.y, bi1.z, bi1.w};
    #pragma unroll
    for (int jt = 0; jt < 8; jt++){
      float b = bia[jt];
      f32x4 c = {b, b, b, b};
      acc[0][jt] = c; acc[1][jt] = c;
    }
  }

  bf16x8 c0 = load8(pa0 + aq), c1 = load8(pa1 + aq);
  bf16x8 c2 = load8(px0 + aq), c3 = load8(px1 + aq);
  #pragma unroll
  for (int kt = 0; kt < 4; kt++){
    bf16x8 n0 = c0, n1 = c1, n2 = c2, n3 = c3;
    if (kt < 3){
      int ao = (kt + 1) * 32 + aq;
      n0 = load8(pa0 + ao); n1 = load8(pa1 + ao);
      n2 = load8(px0 + ao); n3 = load8(px1 + ao);
    }
    #pragma unroll
    for (int jt = 0; jt < 8; jt++){
      bf16x8 bL = load8(Wf + ((kt * 16 + jt) * 64 + lane) * 8);
      bf16x8 bR = load8(Wf + ((kt * 16 + 8 + jt) * 64 + lane) * 8);
      acc[0][jt] = __builtin_amdgcn_mfma_f32_16x16x32_bf16(c0, bL, acc[0][jt], 0, 0, 0);
      acc[1][jt] = __builtin_amdgcn_mfma_f32_16x16x32_bf16(c1, bL, acc[1][jt], 0, 0, 0);
      acc[0][jt] = __builtin_amdgcn_mfma_f32_16x16x32_bf16(c2, bR, acc[0][jt], 0, 0, 0);
      acc[1][jt] = __builtin_amdgcn_mfma_f32_16x16x32_bf16(c3, bR, acc[1][jt], 0, 0, 0);
    }
    c0 = n0; c1 = n1; c2 = n2; c3 = n3;
  }

  // epilogue: constants loaded here (not live across the MFMA loop)
  float4 g0 = *(const float4*)(gamma + l16 * 8);
  float4 g1 = *(const float4*)(gamma + l16 * 8 + 4);
  float4 be0 = *(const float4*)(beta + l16 * 8);
  float4 be1 = *(const float4*)(beta + l16 * 8 + 4);
  float gg[8] = {g0.x, g0.y, g0.z, g0.w, g1.x, g1.y, g1.z, g1.w};
  float bb[8] = {be0.x, be0.y, be0.z, be0.w, be1.x, be1.y, be1.z, be1.w};

  #pragma unroll
  for (int rt = 0; rt < 2; rt++){
    float s1[4] = {0,0,0,0}, s2[4] = {0,0,0,0};
    #pragma unroll
    for (int jt = 0; jt < 8; jt++){
      #pragma unroll
      for (int r = 0; r < 4; r++){ float v = acc[rt][jt][r]; s1[r] += v; s2[r] += v * v; }
    }
    #pragma unroll
    for (int m = 1; m < 16; m <<= 1){
      #pragma unroll
      for (int r = 0; r < 4; r++){
        s1[r] += __shfl_xor(s1[r], m, 64);
        s2[r] += __shfl_xor(s2[r], m, 64);
      }
    }
    #pragma unroll
    for (int r = 0; r < 4; r++){
      float mu = s1[r] * (1.f / 128.f);
      float var = s2[r] * (1.f / 128.f) - mu * mu;
      float rs = rsqrtf(var + 1e-5f);
      int row = rowbase + rt * 16 + quad * 4 + r;
      int rowc = row < N ? row : N - 1;
      uint rw[4] = {0u, 0u, 0u, 0u};
      if (HAS_RES){
        uint4 rv = *(const uint4*)(xin + (size_t)rowc * HID + l16 * 8);
        rw[0] = rv.x; rw[1] = rv.y; rw[2] = rv.z; rw[3] = rv.w;
      }
      uint ow[4];
      #pragma unroll
      for (int p = 0; p < 4; p++){
        float v0 = (acc[rt][2 * p][r] - mu) * rs * gg[2 * p] + bb[2 * p];
        float v1 = (acc[rt][2 * p + 1][r] - mu) * rs * gg[2 * p + 1] + bb[2 * p + 1];
        v0 = fmaxf(v0, 0.f);
        v1 = fmaxf(v1, 0.f);
        if (HAS_RES){
          v0 += bf2f((ushort)(rw[p] & 0xffffu));
          v1 += bf2f((ushort)(rw[p] >> 16));
        }
        ow[p] = (uint)f2bf(v0) | ((uint)f2bf(v1) << 16);
      }
      uint4 o;
      o.x = ow[0]; o.y = ow[1]; o.z = ow[2]; o.w = ow[3];
      if (row < N)
        *(uint4*)(xout + (size_t)row * HID + l16 * 8) = o;
    }
  }
}

// ---------------- JK: out = [emb,x1,x2,x3] @ jkW^T + jkb  (out f32) ----------------
// v5: no LDS/barriers, one 128-row tile per block; flattened 16 ktg-groups with
// 1-deep A prefetch (8 live A-regs); bias added in epilogue (acc zero-init).
__global__ __launch_bounds__(256, 4) void k_jk(
    const ushort* __restrict__ emb, const ushort* __restrict__ x1,
    const ushort* __restrict__ x2, const ushort* __restrict__ x3,
    const ushort* __restrict__ Wf,   // [kt16][jt8][lane64][8] bf16 (col-permuted)
    const float* __restrict__ jkb, float* __restrict__ out, int N){
  int tid = threadIdx.x;
  int wv = tid >> 6, lane = tid & 63;
  int quad = lane >> 4, l16 = lane & 15;
  int rowbase = blockIdx.x * 128 + wv * 32;
  int r0 = rowbase + l16;      if (r0 >= N) r0 = N - 1;
  int r1 = rowbase + 16 + l16; if (r1 >= N) r1 = N - 1;
  int aq = quad * 8;
  size_t o0 = (size_t)r0 * HID, o1 = (size_t)r1 * HID;

  f32x4 acc[2][8];
  #pragma unroll
  for (int jt = 0; jt < 8; jt++){
    f32x4 z = {0.f, 0.f, 0.f, 0.f};
    acc[0][jt] = z; acc[1][jt] = z;
  }

  const ushort* srcs[4] = {emb, x1, x2, x3};
  bf16x8 a0 = load8(emb + o0 + aq);
  bf16x8 a1 = load8(emb + o1 + aq);
  #pragma unroll
  for (int ktg = 0; ktg < 16; ktg++){
    bf16x8 n0 = a0, n1 = a1;
    if (ktg < 15){
      const ushort* sp = srcs[(ktg + 1) >> 2];   // compile-time after unroll
      int ao = ((ktg + 1) & 3) * 32 + aq;
      n0 = load8(sp + o0 + ao);
      n1 = load8(sp + o1 + ao);
    }
    #pragma unroll
    for (int jt = 0; jt < 8; jt++){
      bf16x8 bW = load8(Wf + ((ktg * 8 + jt) * 64 + lane) * 8);
      acc[0][jt] = __builtin_amdgcn_mfma_f32_16x16x32_bf16(a0, bW, acc[0][jt], 0, 0, 0);
      acc[1][jt] = __builtin_amdgcn_mfma_f32_16x16x32_bf16(a1, bW, acc[1][jt], 0, 0, 0);
    }
    a0 = n0; a1 = n1;
  }

  // epilogue: bias add here
  float4 jb0 = *(const float4*)(jkb + l16 * 4);
  float4 jb1 = *(const float4*)(jkb + 64 + l16 * 4);
  float bia[8] = {jb0.x, jb0.y, jb0.z, jb0.w, jb1.x, jb1.y, jb1.z, jb1.w};

  #pragma unroll
  for (int rt = 0; rt < 2; rt++){
    #pragma unroll
    for (int r = 0; r < 4; r++){
      int row = rowbase + rt * 16 + quad * 4 + r;
      if (row < N){
        f32x4 v0 = {acc[rt][0][r] + bia[0], acc[rt][1][r] + bia[1],
                    acc[rt][2][r] + bia[2], acc[rt][3][r] + bia[3]};
        f32x4 v1 = {acc[rt][4][r] + bia[4], acc[rt][5][r] + bia[5],
                    acc[rt][6][r] + bia[6], acc[rt][7][r] + bia[7]};
        *(f32x4*)(out + (size_t)row * HID + l16 * 4) = v0;
        *(f32x4*)(out + (size_t)row * HID + 64 + l16 * 4) = v1;
      }
    }
  }
}

extern "C" void kernel_launch(void* const* d_in, const int* in_sizes, int n_in,
                              void* d_out, int out_size, void* d_ws, size_t ws_size,
                              hipStream_t stream){
  const float* emb   = (const float*)d_in[0];
  const float* Wl    = (const float*)d_in[1];
  const float* bl    = (const float*)d_in[2];
  const float* Wr    = (const float*)d_in[3];
  const float* gamma = (const float*)d_in[4];
  const float* beta  = (const float*)d_in[5];
  const float* jkW   = (const float*)d_in[6];
  const float* jkb   = (const float*)d_in[7];
  const int*   eidx  = (const int*)d_in[8];
  int N = in_sizes[0] / HID;
  int E = in_sizes[8] / 2;
  const int* src = eidx;
  const int* dst = eidx + E;
  float* out = (float*)d_out;

  int NB = (N + 127) >> BSHIFT;        // coarse buckets of 128 nodes
  int es = (E + NBLK - 1) / NBLK;      // edges per slice block

  // workspace carve (256B aligned)
  char* w = (char*)d_ws;
  auto carve = [&](size_t bytes) -> char* {
    char* p = w; w += (bytes + 255) & ~(size_t)255; return p;
  };
  int Npad = ((N + 127) / 128) * 128;
  int* rowcnt   = (int*)carve((size_t)NBLK * NB * 4);
  int* bbase    = (int*)carve((size_t)(NB + 1) * 4);
  uint* binned  = (uint*)carve((size_t)E * 4);
  int* cnt      = (int*)carve((size_t)N * 4);
  int* offs     = (int*)carve((size_t)N * 4);
  int* csr      = (int*)carve((size_t)E * 4);
  ushort* Wfrag = (ushort*)carve((size_t)3 * 32768 * 2);
  ushort* jkWf  = (ushort*)carve((size_t)65536 * 2);
  ushort* embbf = (ushort*)carve((size_t)Npad * HID * 2);
  ushort* agg   = (ushort*)carve((size_t)Npad * HID * 2);
  ushort* x1    = (ushort*)carve((size_t)Npad * HID * 2);
  ushort* x2    = (ushort*)carve((size_t)Npad * HID * 2);
  ushort* x3    = (ushort*)carve((size_t)Npad * HID * 2);

  // weight transforms + emb cast
  int nEmb = N * HID;
  k_cvtw<<<(3 * 32768 + 255) / 256, 256, 0, stream>>>(Wl, Wr, Wfrag, 3 * 32768);
  k_cvtjk<<<65536 / 256, 256, 0, stream>>>(jkW, jkWf);
  k_cvt<<<(nEmb + 255) / 256, 256, 0, stream>>>(emb, embbf, nEmb);

  // deterministic two-level CSR build
  k_count<<<NBLK, 1024, 0, stream>>>(dst, rowcnt, E, NB, es);
  k_colscan<<<1, 1024, 0, stream>>>(rowcnt, bbase, NB, NBLK);
  k_place<<<NBLK, 1024, 0, stream>>>(src, dst, rowcnt, binned, E, NB, es);
  k_bpass<<<NB, 256, 0, stream>>>(binned, bbase, csr, offs, cnt, N);

  int aggBlocks = (N + 3) / 4;
  int gemmBlocks = (N + 127) / 128;   // one 128-row tile per block

  // layer 0 (no residual)
  k_aggregate<<<aggBlocks, 256, 0, stream>>>(embbf, csr, offs, cnt, agg, N);
  k_layer<0><<<gemmBlocks, 256, 0, stream>>>(agg, embbf, Wfrag, bl, gamma, beta, x1, N);
  // layer 1
  k_aggregate<<<aggBlocks, 256, 0, stream>>>(x1, csr, offs, cnt, agg, N);
  k_layer<1><<<gemmBlocks, 256, 0, stream>>>(agg, x1, Wfrag + 32768, bl + HID,
                                             gamma + HID, beta + HID, x2, N);
  // layer 2
  k_aggregate<<<aggBlocks, 256, 0, stream>>>(x2, csr, offs, cnt, agg, N);
  k_layer<1><<<gemmBlocks, 256, 0, stream>>>(agg, x2, Wfrag + 2 * 32768, bl + 2 * HID,
                                             gamma + 2 * HID, beta + 2 * HID, x3, N);
  // jumping knowledge projection
  k_jk<<<gemmBlocks, 256, 0, stream>>>(embbf, x1, x2, x3, jkWf, jkb, out, N);
}